// Round 8
// baseline (8134.121 us; speedup 1.0000x reference)
//
#include <hip/hip_runtime.h>
#include <stdint.h>

#define N_SIZE 4096
#define N_STEPS 512
#define WROW 8192
#define THRESH 10.0f

#define WST_BYTES ((size_t)(N_SIZE + 1) * N_SIZE * 4)   // WsT + zero pad row
#define FLAG_OFF  WST_BYTES
#define FULL_WS   (WST_BYTES + 64)

typedef float f32x4 __attribute__((ext_vector_type(4)));
typedef int   i32x4 __attribute__((ext_vector_type(4)));

#define F4E(v, j) ((j) == 0 ? (v).x : (j) == 1 ? (v).y : (j) == 2 ? (v).z : (v).w)
#define ADD4(a, b) { (a).x += (b).x; (a).y += (b).y; (a).z += (b).z; (a).w += (b).w; }

// ------- zero pad row + burner flag (every launch; ws poisoned once) --------
__global__ __launch_bounds__(256) void k_zero(float* __restrict__ WsT,
                                              unsigned* __restrict__ flag) {
    if (blockIdx.x < 16) {
        WsT[(size_t)N_SIZE * N_SIZE + blockIdx.x * 256 + threadIdx.x] = 0.f;
    } else if (threadIdx.x == 0) {
        *flag = 0u;
    }
}

// ---------------- transpose: WsT[s][o] = W[o*8192 + 4096 + s] ----------------
__global__ __launch_bounds__(256) void k_transpose(const float* __restrict__ W,
                                                   float* __restrict__ WsT) {
    __shared__ float tile[32][33];
    const int bs = blockIdx.x * 32;
    const int bo = blockIdx.y * 32;
    const int tx = threadIdx.x;
    const int ty = threadIdx.y;
#pragma unroll
    for (int j = 0; j < 4; ++j)
        tile[ty + j * 8][tx] = W[(size_t)(bo + ty + j * 8) * WROW + N_SIZE + bs + tx];
    __syncthreads();
#pragma unroll
    for (int j = 0; j < 4; ++j)
        WsT[(size_t)(bs + ty + j * 8) * N_SIZE + bo + tx] = tile[tx][ty + j * 8];
}

// ---------------- GEMM: C[t][o] = sum_k x[t][k] * W[o][k], split-K=2 --------
#define BM 64
#define BN 128
#define BK 16
#define KHALF (N_SIZE / 2)
#define ALD 68
#define BLD 132

__global__ __launch_bounds__(128) void k_gemm(const float* __restrict__ x,
                                              const float* __restrict__ W,
                                              float* __restrict__ dst0,
                                              float* __restrict__ dst1) {
    __shared__ float As[BK][ALD];
    __shared__ float Bs[BK][BLD];
    const int tid = threadIdx.x;
    const int bm = blockIdx.y * BM;
    const int bn = blockIdx.x * BN;
    const int kb0 = blockIdx.z * KHALF;
    float* dst = blockIdx.z ? dst1 : dst0;

    const int m0 = (tid >> 4) << 3;
    const int n0 = (tid & 15) << 2;
    const int ar = tid >> 2;
    const int ac = (tid & 3) << 2;
    const float* Ap = &x[(size_t)(bm + ar) * N_SIZE + kb0 + ac];
    const float* Bp = &W[(size_t)(bn + ar) * WROW + kb0 + ac];

    float4 pa0 = *(const float4*)&Ap[0];
    float4 pa1 = *(const float4*)&Ap[(size_t)32 * N_SIZE];
    float4 pb0 = *(const float4*)&Bp[0];
    float4 pb1 = *(const float4*)&Bp[(size_t)32 * WROW];
    float4 pb2 = *(const float4*)&Bp[(size_t)64 * WROW];
    float4 pb3 = *(const float4*)&Bp[(size_t)96 * WROW];

    float acc[8][8];
#pragma unroll
    for (int i = 0; i < 8; ++i)
#pragma unroll
        for (int j = 0; j < 8; ++j) acc[i][j] = 0.f;

    const int nkt = KHALF / BK;
    for (int kt = 0; kt < nkt; ++kt) {
        __syncthreads();
#pragma unroll
        for (int j = 0; j < 4; ++j) {
            As[ac + j][ar]      = F4E(pa0, j);
            As[ac + j][ar + 32] = F4E(pa1, j);
            Bs[ac + j][ar]      = F4E(pb0, j);
            Bs[ac + j][ar + 32] = F4E(pb1, j);
            Bs[ac + j][ar + 64] = F4E(pb2, j);
            Bs[ac + j][ar + 96] = F4E(pb3, j);
        }
        __syncthreads();
        if (kt + 1 < nkt) {
            const float* Ap2 = Ap + (size_t)(kt + 1) * BK;
            const float* Bp2 = Bp + (size_t)(kt + 1) * BK;
            pa0 = *(const float4*)&Ap2[0];
            pa1 = *(const float4*)&Ap2[(size_t)32 * N_SIZE];
            pb0 = *(const float4*)&Bp2[0];
            pb1 = *(const float4*)&Bp2[(size_t)32 * WROW];
            pb2 = *(const float4*)&Bp2[(size_t)64 * WROW];
            pb3 = *(const float4*)&Bp2[(size_t)96 * WROW];
        }
#pragma unroll
        for (int k = 0; k < BK; ++k) {
            const float4 a0 = *(const float4*)&As[k][m0];
            const float4 a1 = *(const float4*)&As[k][m0 + 4];
            const float4 b0 = *(const float4*)&Bs[k][n0];
            const float4 b1 = *(const float4*)&Bs[k][n0 + 64];
            const float av[8] = {a0.x, a0.y, a0.z, a0.w, a1.x, a1.y, a1.z, a1.w};
            const float bv[8] = {b0.x, b0.y, b0.z, b0.w, b1.x, b1.y, b1.z, b1.w};
#pragma unroll
            for (int i = 0; i < 8; ++i)
#pragma unroll
                for (int j = 0; j < 8; ++j)
                    acc[i][j] = fmaf(av[i], bv[j], acc[i][j]);
        }
    }
#pragma unroll
    for (int i = 0; i < 8; ++i) {
        float* cp = &dst[(size_t)(bm + m0 + i) * N_SIZE + bn];
        const float4 o0 = {acc[i][0], acc[i][1], acc[i][2], acc[i][3]};
        const float4 o1 = {acc[i][4], acc[i][5], acc[i][6], acc[i][7]};
        *(float4*)&cp[n0] = o0;
        *(float4*)&cp[n0 + 64] = o1;
    }
}

__global__ __launch_bounds__(256) void k_reduce(float* __restrict__ acc,
                                                const float* __restrict__ part) {
    const size_t i = ((size_t)blockIdx.x * 256 + threadIdx.x) * 4;
    const float4 a = *(const float4*)&acc[i];
    const float4 b = *(const float4*)&part[i];
    const float4 r = {a.x + b.x, a.y + b.y, a.z + b.z, a.w + b.w};
    *(float4*)&acc[i] = r;
}

// ---------------- scan + clock-pinning burners ----------------
// Block 0: R1-proven 16-wave scan; gather = ONE asm block per 12 columns
// (12 saddr global_load_dwordx4 + single s_waitcnt vmcnt(0) INSIDE the block
// -> the waitcnt-inserter cannot serialize it). Blocks 1..255: dependent-FMA
// spin on the other CUs polling the done-flag, keeping the clock governor at
// high frequency during the 1-2 ms serial phase. All 256 blocks co-resident
// (<= 2048 thr/CU, 33 KB LDS) -> no deadlock; output is unaffected by timing.
__global__ __launch_bounds__(1024) void k_scanB(const float* __restrict__ WsT,
                                                float* __restrict__ spk_out,
                                                float* __restrict__ mem_out,
                                                unsigned* __restrict__ flag) {
    if (blockIdx.x != 0) {
        float a = 1.0f + (float)threadIdx.x * 1e-7f;
        while (__hip_atomic_load(flag, __ATOMIC_ACQUIRE,
                                 __HIP_MEMORY_SCOPE_AGENT) == 0u) {
#pragma unroll 64
            for (int i = 0; i < 256; ++i) a = fmaf(a, 0.99999988f, 1e-7f);
        }
        asm volatile("" :: "v"(a));   // keep the chain live (no DCE)
        return;
    }

    __shared__ int lst[2][N_SIZE + 12];
    __shared__ int wcnt[16];
    const int tid = threadIdx.x;
    const int wave = tid >> 6;
    const int lane = tid & 63;
    const int base = tid << 2;          // 4 neurons: base..base+3
    const int lb = base << 2;           // byte offset within a row
    const unsigned long long below = (lane == 0) ? 0ULL : (~0ULL >> (64 - lane));

    f32x4 mem = {0.f, 0.f, 0.f, 0.f};
    int tot = 0, buf = 0;

    f32x4 cn = *(const f32x4*)&mem_out[base];

    for (int t = 0; t < N_STEPS; ++t) {
        f32x4 c = cn;
        // prefetch next cur_x row (completes during this step's gather)
        const int tn = (t + 1 < N_STEPS) ? (t + 1) : t;
        cn = *(const f32x4*)&mem_out[(size_t)tn * N_SIZE + base];

        // ---- gather: 12 columns per SINGLE asm block, one vmcnt round ----
        const int* lp = lst[buf];
        for (int i0 = 0; i0 < tot; i0 += 12) {
            const i32x4 ia = *(const i32x4*)&lp[i0];
            const i32x4 ib = *(const i32x4*)&lp[i0 + 4];
            const i32x4 ic = *(const i32x4*)&lp[i0 + 8];
            const int o0 = (__builtin_amdgcn_readfirstlane(ia.x) << 14) + lb;
            const int o1 = (__builtin_amdgcn_readfirstlane(ia.y) << 14) + lb;
            const int o2 = (__builtin_amdgcn_readfirstlane(ia.z) << 14) + lb;
            const int o3 = (__builtin_amdgcn_readfirstlane(ia.w) << 14) + lb;
            const int o4 = (__builtin_amdgcn_readfirstlane(ib.x) << 14) + lb;
            const int o5 = (__builtin_amdgcn_readfirstlane(ib.y) << 14) + lb;
            const int o6 = (__builtin_amdgcn_readfirstlane(ib.z) << 14) + lb;
            const int o7 = (__builtin_amdgcn_readfirstlane(ib.w) << 14) + lb;
            const int o8 = (__builtin_amdgcn_readfirstlane(ic.x) << 14) + lb;
            const int o9 = (__builtin_amdgcn_readfirstlane(ic.y) << 14) + lb;
            const int oA = (__builtin_amdgcn_readfirstlane(ic.z) << 14) + lb;
            const int oB = (__builtin_amdgcn_readfirstlane(ic.w) << 14) + lb;
            f32x4 r0, r1, r2, r3, r4, r5, r6, r7, r8, r9, rA, rB;
            asm volatile(
                "global_load_dwordx4 %[r0], %[o0], %[B]\n\t"
                "global_load_dwordx4 %[r1], %[o1], %[B]\n\t"
                "global_load_dwordx4 %[r2], %[o2], %[B]\n\t"
                "global_load_dwordx4 %[r3], %[o3], %[B]\n\t"
                "global_load_dwordx4 %[r4], %[o4], %[B]\n\t"
                "global_load_dwordx4 %[r5], %[o5], %[B]\n\t"
                "global_load_dwordx4 %[r6], %[o6], %[B]\n\t"
                "global_load_dwordx4 %[r7], %[o7], %[B]\n\t"
                "global_load_dwordx4 %[r8], %[o8], %[B]\n\t"
                "global_load_dwordx4 %[r9], %[o9], %[B]\n\t"
                "global_load_dwordx4 %[rA], %[oA], %[B]\n\t"
                "global_load_dwordx4 %[rB], %[oB], %[B]\n\t"
                "s_waitcnt vmcnt(0)"
                : [r0] "=&v"(r0), [r1] "=&v"(r1), [r2] "=&v"(r2),
                  [r3] "=&v"(r3), [r4] "=&v"(r4), [r5] "=&v"(r5),
                  [r6] "=&v"(r6), [r7] "=&v"(r7), [r8] "=&v"(r8),
                  [r9] "=&v"(r9), [rA] "=&v"(rA), [rB] "=&v"(rB)
                : [o0] "v"(o0), [o1] "v"(o1), [o2] "v"(o2), [o3] "v"(o3),
                  [o4] "v"(o4), [o5] "v"(o5), [o6] "v"(o6), [o7] "v"(o7),
                  [o8] "v"(o8), [o9] "v"(o9), [oA] "v"(oA), [oB] "v"(oB),
                  [B] "s"(WsT)
                : "memory");
            c += r0; c += r1; c += r2; c += r3; c += r4; c += r5;
            c += r6; c += r7; c += r8; c += r9; c += rA; c += rB;
        }

        // ---- membrane update, threshold ----
        mem += c;
        const bool s0 = mem.x > THRESH, s1 = mem.y > THRESH;
        const bool s2 = mem.z > THRESH, s3 = mem.w > THRESH;
        mem.x -= s0 ? THRESH : 0.f;  mem.y -= s1 ? THRESH : 0.f;
        mem.z -= s2 ? THRESH : 0.f;  mem.w -= s3 ? THRESH : 0.f;

        // ---- ballots + outputs ----
        const unsigned long long B0 = __ballot(s0), B1 = __ballot(s1);
        const unsigned long long B2 = __ballot(s2), B3 = __ballot(s3);
        const int pre = __popcll(B0 & below) + __popcll(B1 & below) +
                        __popcll(B2 & below) + __popcll(B3 & below);
        if (lane == 0)
            wcnt[wave] = __popcll(B0) + __popcll(B1) + __popcll(B2) + __popcll(B3);

        const f32x4 sp = {s0 ? 1.f : 0.f, s1 ? 1.f : 0.f,
                          s2 ? 1.f : 0.f, s3 ? 1.f : 0.f};
        *(f32x4*)&spk_out[(size_t)t * N_SIZE + base] = sp;
        *(f32x4*)&mem_out[(size_t)t * N_SIZE + base] = mem;

        __syncthreads();   // bar1: wcnt visible; gather reads of lst[buf] done

        int woff = 0, tt = 0;
#pragma unroll
        for (int w = 0; w < 16; ++w) {
            const int cw = wcnt[w];
            if (w < wave) woff += cw;
            tt += cw;
        }
        int* nxt = lst[buf ^ 1];
        int off = woff + pre;
        if (s0) nxt[off++] = base + 0;
        if (s1) nxt[off++] = base + 1;
        if (s2) nxt[off++] = base + 2;
        if (s3) nxt[off++] = base + 3;
        if (tid < 12) nxt[tt + tid] = N_SIZE;   // pad -> zero row

        __syncthreads();   // bar2: next list ready

        tot = tt;
        buf ^= 1;
    }

    if (tid == 0)
        __hip_atomic_store(flag, 1u, __ATOMIC_RELEASE, __HIP_MEMORY_SCOPE_AGENT);
}

// ---------------- fallback: single-WG scan (no/partial ws) ----------------
template <int USE_WST>
__global__ __launch_bounds__(1024) void k_scan1(const float* __restrict__ WsT,
                                                const float* __restrict__ W,
                                                float* __restrict__ spk_out,
                                                float* __restrict__ mem_out) {
    __shared__ int lists[2][N_SIZE];
    __shared__ int wcnt[16];
    const int tid = threadIdx.x;
    const int wave = tid >> 6;
    const int lane = tid & 63;
    const int base = tid << 2;
    const unsigned long long below = (lane == 0) ? 0ULL : (~0ULL >> (64 - lane));

    float4 mem = {0.f, 0.f, 0.f, 0.f};
    int cnt = 0, cur = 0;
    for (int t = 0; t < N_STEPS; ++t) {
        float* mrow = &mem_out[(size_t)t * N_SIZE + base];
        float4 c = *(const float4*)mrow;
        const int* lstp = lists[cur];
        for (int i = 0; i < cnt; ++i) {
            const int s = lstp[i];
            float4 w0;
            if (USE_WST) {
                w0 = *(const float4*)&WsT[(size_t)s * N_SIZE + base];
            } else {
                w0.x = W[(size_t)(base + 0) * WROW + N_SIZE + s];
                w0.y = W[(size_t)(base + 1) * WROW + N_SIZE + s];
                w0.z = W[(size_t)(base + 2) * WROW + N_SIZE + s];
                w0.w = W[(size_t)(base + 3) * WROW + N_SIZE + s];
            }
            ADD4(c, w0)
        }
        ADD4(mem, c)
        const bool s0 = mem.x > THRESH, s1 = mem.y > THRESH;
        const bool s2 = mem.z > THRESH, s3 = mem.w > THRESH;
        mem.x -= s0 ? THRESH : 0.f;  mem.y -= s1 ? THRESH : 0.f;
        mem.z -= s2 ? THRESH : 0.f;  mem.w -= s3 ? THRESH : 0.f;
        const float4 spkv = {s0 ? 1.f : 0.f, s1 ? 1.f : 0.f,
                             s2 ? 1.f : 0.f, s3 ? 1.f : 0.f};
        *(float4*)&spk_out[(size_t)t * N_SIZE + base] = spkv;
        *(float4*)mrow = mem;
        const unsigned long long b0 = __ballot(s0), b1 = __ballot(s1);
        const unsigned long long b2 = __ballot(s2), b3 = __ballot(s3);
        const int pre = __popcll(b0 & below) + __popcll(b1 & below) +
                        __popcll(b2 & below) + __popcll(b3 & below);
        if (lane == 0)
            wcnt[wave] = __popcll(b0) + __popcll(b1) + __popcll(b2) + __popcll(b3);
        __syncthreads();
        int woff = 0, total = 0;
#pragma unroll
        for (int wv = 0; wv < 16; ++wv) {
            const int cw = wcnt[wv];
            if (wv < wave) woff += cw;
            total += cw;
        }
        int* nxt = lists[cur ^ 1];
        int off = woff + pre;
        if (s0) nxt[off++] = base;
        if (s1) nxt[off++] = base + 1;
        if (s2) nxt[off++] = base + 2;
        if (s3) nxt[off++] = base + 3;
        __syncthreads();
        cnt = total;
        cur ^= 1;
    }
}

extern "C" void kernel_launch(void* const* d_in, const int* in_sizes, int n_in,
                              void* d_out, int out_size, void* d_ws, size_t ws_size,
                              hipStream_t stream) {
    const float* x = (const float*)d_in[0];
    const float* W = (const float*)d_in[1];
    float* spk_out = (float*)d_out;
    float* mem_out = spk_out + (size_t)N_STEPS * N_SIZE;
    float* WsT = (float*)d_ws;
    unsigned* flag = (unsigned*)((char*)d_ws + FLAG_OFF);
    const bool full = ws_size >= FULL_WS;
    const bool use_wst = ws_size >= (size_t)N_SIZE * N_SIZE * 4;

    if (full) {
        k_zero<<<17, 256, 0, stream>>>(WsT, flag);
        k_transpose<<<dim3(N_SIZE / 32, N_SIZE / 32), dim3(32, 8), 0, stream>>>(W, WsT);
    } else if (use_wst) {
        k_transpose<<<dim3(N_SIZE / 32, N_SIZE / 32), dim3(32, 8), 0, stream>>>(W, WsT);
    }

    k_gemm<<<dim3(N_SIZE / BN, N_STEPS / BM, 2), 128, 0, stream>>>(x, W, mem_out, spk_out);
    k_reduce<<<(N_STEPS * N_SIZE) / (256 * 4), 256, 0, stream>>>(mem_out, spk_out);

    if (full) {
        k_scanB<<<256, 1024, 0, stream>>>(WsT, spk_out, mem_out, flag);
    } else if (use_wst) {
        k_scan1<1><<<1, 1024, 0, stream>>>(WsT, W, spk_out, mem_out);
    } else {
        k_scan1<0><<<1, 1024, 0, stream>>>(WsT, W, spk_out, mem_out);
    }
}

// Round 9
// 1753.926 us; speedup vs baseline: 4.6377x; 4.6377x over previous
//
#include <hip/hip_runtime.h>
#include <stdint.h>

#define N_SIZE 4096
#define N_STEPS 512
#define WROW 8192
#define THRESH 10.0f

#define WST_BYTES ((size_t)(N_SIZE + 1) * N_SIZE * 4)   // WsT + zero pad row
#define FLAG_OFF  WST_BYTES
#define SMEM_OFF  (WST_BYTES + 64)
#define SLST_OFF  (SMEM_OFF + (size_t)N_SIZE * 4)
#define FULL_WS   (SLST_OFF + (size_t)(N_SIZE + 13) * 4)

typedef float f32x4 __attribute__((ext_vector_type(4)));
typedef int   i32x4 __attribute__((ext_vector_type(4)));

#define F4E(v, j) ((j) == 0 ? (v).x : (j) == 1 ? (v).y : (j) == 2 ? (v).z : (v).w)
#define ADD4(a, b) { (a).x += (b).x; (a).y += (b).y; (a).z += (b).z; (a).w += (b).w; }

// ------- zero pad row + burner flag (every launch; ws poisoned once) --------
__global__ __launch_bounds__(256) void k_zero(float* __restrict__ WsT,
                                              unsigned* __restrict__ flag) {
    if (blockIdx.x < 16) {
        WsT[(size_t)N_SIZE * N_SIZE + blockIdx.x * 256 + threadIdx.x] = 0.f;
    } else if (threadIdx.x == 0) {
        *flag = 0u;
    }
}

// ---------------- transpose: WsT[s][o] = W[o*8192 + 4096 + s] ----------------
__global__ __launch_bounds__(256) void k_transpose(const float* __restrict__ W,
                                                   float* __restrict__ WsT) {
    __shared__ float tile[32][33];
    const int bs = blockIdx.x * 32;
    const int bo = blockIdx.y * 32;
    const int tx = threadIdx.x;
    const int ty = threadIdx.y;
#pragma unroll
    for (int j = 0; j < 4; ++j)
        tile[ty + j * 8][tx] = W[(size_t)(bo + ty + j * 8) * WROW + N_SIZE + bs + tx];
    __syncthreads();
#pragma unroll
    for (int j = 0; j < 4; ++j)
        WsT[(size_t)(bs + ty + j * 8) * N_SIZE + bo + tx] = tile[tx][ty + j * 8];
}

// ---------------- GEMM: C[t][o] = sum_k x[t][k] * W[o][k], split-K=2 --------
#define BM 64
#define BN 128
#define BK 16
#define KHALF (N_SIZE / 2)
#define ALD 68
#define BLD 132

__global__ __launch_bounds__(128) void k_gemm(const float* __restrict__ x,
                                              const float* __restrict__ W,
                                              float* __restrict__ dst0,
                                              float* __restrict__ dst1) {
    __shared__ float As[BK][ALD];
    __shared__ float Bs[BK][BLD];
    const int tid = threadIdx.x;
    const int bm = blockIdx.y * BM;
    const int bn = blockIdx.x * BN;
    const int kb0 = blockIdx.z * KHALF;
    float* dst = blockIdx.z ? dst1 : dst0;

    const int m0 = (tid >> 4) << 3;
    const int n0 = (tid & 15) << 2;
    const int ar = tid >> 2;
    const int ac = (tid & 3) << 2;
    const float* Ap = &x[(size_t)(bm + ar) * N_SIZE + kb0 + ac];
    const float* Bp = &W[(size_t)(bn + ar) * WROW + kb0 + ac];

    float4 pa0 = *(const float4*)&Ap[0];
    float4 pa1 = *(const float4*)&Ap[(size_t)32 * N_SIZE];
    float4 pb0 = *(const float4*)&Bp[0];
    float4 pb1 = *(const float4*)&Bp[(size_t)32 * WROW];
    float4 pb2 = *(const float4*)&Bp[(size_t)64 * WROW];
    float4 pb3 = *(const float4*)&Bp[(size_t)96 * WROW];

    float acc[8][8];
#pragma unroll
    for (int i = 0; i < 8; ++i)
#pragma unroll
        for (int j = 0; j < 8; ++j) acc[i][j] = 0.f;

    const int nkt = KHALF / BK;
    for (int kt = 0; kt < nkt; ++kt) {
        __syncthreads();
#pragma unroll
        for (int j = 0; j < 4; ++j) {
            As[ac + j][ar]      = F4E(pa0, j);
            As[ac + j][ar + 32] = F4E(pa1, j);
            Bs[ac + j][ar]      = F4E(pb0, j);
            Bs[ac + j][ar + 32] = F4E(pb1, j);
            Bs[ac + j][ar + 64] = F4E(pb2, j);
            Bs[ac + j][ar + 96] = F4E(pb3, j);
        }
        __syncthreads();
        if (kt + 1 < nkt) {
            const float* Ap2 = Ap + (size_t)(kt + 1) * BK;
            const float* Bp2 = Bp + (size_t)(kt + 1) * BK;
            pa0 = *(const float4*)&Ap2[0];
            pa1 = *(const float4*)&Ap2[(size_t)32 * N_SIZE];
            pb0 = *(const float4*)&Bp2[0];
            pb1 = *(const float4*)&Bp2[(size_t)32 * WROW];
            pb2 = *(const float4*)&Bp2[(size_t)64 * WROW];
            pb3 = *(const float4*)&Bp2[(size_t)96 * WROW];
        }
#pragma unroll
        for (int k = 0; k < BK; ++k) {
            const float4 a0 = *(const float4*)&As[k][m0];
            const float4 a1 = *(const float4*)&As[k][m0 + 4];
            const float4 b0 = *(const float4*)&Bs[k][n0];
            const float4 b1 = *(const float4*)&Bs[k][n0 + 64];
            const float av[8] = {a0.x, a0.y, a0.z, a0.w, a1.x, a1.y, a1.z, a1.w};
            const float bv[8] = {b0.x, b0.y, b0.z, b0.w, b1.x, b1.y, b1.z, b1.w};
#pragma unroll
            for (int i = 0; i < 8; ++i)
#pragma unroll
                for (int j = 0; j < 8; ++j)
                    acc[i][j] = fmaf(av[i], bv[j], acc[i][j]);
        }
    }
#pragma unroll
    for (int i = 0; i < 8; ++i) {
        float* cp = &dst[(size_t)(bm + m0 + i) * N_SIZE + bn];
        const float4 o0 = {acc[i][0], acc[i][1], acc[i][2], acc[i][3]};
        const float4 o1 = {acc[i][4], acc[i][5], acc[i][6], acc[i][7]};
        *(float4*)&cp[n0] = o0;
        *(float4*)&cp[n0 + 64] = o1;
    }
}

__global__ __launch_bounds__(256) void k_reduce(float* __restrict__ acc,
                                                const float* __restrict__ part) {
    const size_t i = ((size_t)blockIdx.x * 256 + threadIdx.x) * 4;
    const float4 a = *(const float4*)&acc[i];
    const float4 b = *(const float4*)&part[i];
    const float4 r = {a.x + b.x, a.y + b.y, a.z + b.z, a.w + b.w};
    *(float4*)&acc[i] = r;
}

// ---------------- A/B scan: identical scan, with/without clock burners -----
// Block 0: 16-wave scan (R8 asm 12-col single-block gather, correctness-
// proven). Blocks >0 (BURN=1 only): dependent-FMA spin to keep SCLK up;
// poll = RELAXED agent atomic load of one line every ~8k cycles + s_sleep
// (no acquire fences -> none of R8's L2 poisoning). State handoff via ws
// between the two scan dispatches (proven in R4).
template <int BURN>
__global__ __launch_bounds__(1024) void k_scan_ab(const float* __restrict__ WsT,
                                                  float* __restrict__ spk_out,
                                                  float* __restrict__ mem_out,
                                                  float* __restrict__ smem,
                                                  int* __restrict__ slst,
                                                  unsigned* __restrict__ flag,
                                                  int t0, int t1) {
    if (BURN && blockIdx.x != 0) {
        float a = 1.0f + (float)threadIdx.x * 1e-7f;
        for (;;) {
#pragma unroll 32
            for (int i = 0; i < 2048; ++i) a = fmaf(a, 0.99999988f, 1e-7f);
            if (__hip_atomic_load(flag, __ATOMIC_RELAXED,
                                  __HIP_MEMORY_SCOPE_AGENT) != 0u) break;
            __builtin_amdgcn_s_sleep(8);
        }
        asm volatile("" :: "v"(a));   // keep chain live
        return;
    }

    __shared__ int lst[2][N_SIZE + 12];
    __shared__ int wcnt[16];
    const int tid = threadIdx.x;
    const int wave = tid >> 6;
    const int lane = tid & 63;
    const int base = tid << 2;          // 4 neurons: base..base+3
    const int lb = base << 2;           // byte offset within a row
    const unsigned long long below = (lane == 0) ? 0ULL : (~0ULL >> (64 - lane));

    f32x4 mem = {0.f, 0.f, 0.f, 0.f};
    int tot = 0, buf = 0;

    if (t0 != 0) {      // restore state from first dispatch
        mem = *(const f32x4*)&smem[base];
        for (int i = tid; i < N_SIZE + 12; i += 1024) lst[0][i] = slst[i];
        tot = slst[N_SIZE + 12];
        __syncthreads();
    }

    f32x4 cn = *(const f32x4*)&mem_out[(size_t)t0 * N_SIZE + base];

    for (int t = t0; t < t1; ++t) {
        f32x4 c = cn;
        const int tn = (t + 1 < N_STEPS) ? (t + 1) : t;
        cn = *(const f32x4*)&mem_out[(size_t)tn * N_SIZE + base];

        // ---- gather: 12 columns per single asm block, one vmcnt round ----
        const int* lp = lst[buf];
        for (int i0 = 0; i0 < tot; i0 += 12) {
            const i32x4 ia = *(const i32x4*)&lp[i0];
            const i32x4 ib = *(const i32x4*)&lp[i0 + 4];
            const i32x4 ic = *(const i32x4*)&lp[i0 + 8];
            const int o0 = (__builtin_amdgcn_readfirstlane(ia.x) << 14) + lb;
            const int o1 = (__builtin_amdgcn_readfirstlane(ia.y) << 14) + lb;
            const int o2 = (__builtin_amdgcn_readfirstlane(ia.z) << 14) + lb;
            const int o3 = (__builtin_amdgcn_readfirstlane(ia.w) << 14) + lb;
            const int o4 = (__builtin_amdgcn_readfirstlane(ib.x) << 14) + lb;
            const int o5 = (__builtin_amdgcn_readfirstlane(ib.y) << 14) + lb;
            const int o6 = (__builtin_amdgcn_readfirstlane(ib.z) << 14) + lb;
            const int o7 = (__builtin_amdgcn_readfirstlane(ib.w) << 14) + lb;
            const int o8 = (__builtin_amdgcn_readfirstlane(ic.x) << 14) + lb;
            const int o9 = (__builtin_amdgcn_readfirstlane(ic.y) << 14) + lb;
            const int oA = (__builtin_amdgcn_readfirstlane(ic.z) << 14) + lb;
            const int oB = (__builtin_amdgcn_readfirstlane(ic.w) << 14) + lb;
            f32x4 r0, r1, r2, r3, r4, r5, r6, r7, r8, r9, rA, rB;
            asm volatile(
                "global_load_dwordx4 %[r0], %[o0], %[B]\n\t"
                "global_load_dwordx4 %[r1], %[o1], %[B]\n\t"
                "global_load_dwordx4 %[r2], %[o2], %[B]\n\t"
                "global_load_dwordx4 %[r3], %[o3], %[B]\n\t"
                "global_load_dwordx4 %[r4], %[o4], %[B]\n\t"
                "global_load_dwordx4 %[r5], %[o5], %[B]\n\t"
                "global_load_dwordx4 %[r6], %[o6], %[B]\n\t"
                "global_load_dwordx4 %[r7], %[o7], %[B]\n\t"
                "global_load_dwordx4 %[r8], %[o8], %[B]\n\t"
                "global_load_dwordx4 %[r9], %[o9], %[B]\n\t"
                "global_load_dwordx4 %[rA], %[oA], %[B]\n\t"
                "global_load_dwordx4 %[rB], %[oB], %[B]\n\t"
                "s_waitcnt vmcnt(0)"
                : [r0] "=&v"(r0), [r1] "=&v"(r1), [r2] "=&v"(r2),
                  [r3] "=&v"(r3), [r4] "=&v"(r4), [r5] "=&v"(r5),
                  [r6] "=&v"(r6), [r7] "=&v"(r7), [r8] "=&v"(r8),
                  [r9] "=&v"(r9), [rA] "=&v"(rA), [rB] "=&v"(rB)
                : [o0] "v"(o0), [o1] "v"(o1), [o2] "v"(o2), [o3] "v"(o3),
                  [o4] "v"(o4), [o5] "v"(o5), [o6] "v"(o6), [o7] "v"(o7),
                  [o8] "v"(o8), [o9] "v"(o9), [oA] "v"(oA), [oB] "v"(oB),
                  [B] "s"(WsT)
                : "memory");
            c += r0; c += r1; c += r2; c += r3; c += r4; c += r5;
            c += r6; c += r7; c += r8; c += r9; c += rA; c += rB;
        }

        // ---- membrane update, threshold ----
        mem += c;
        const bool s0 = mem.x > THRESH, s1 = mem.y > THRESH;
        const bool s2 = mem.z > THRESH, s3 = mem.w > THRESH;
        mem.x -= s0 ? THRESH : 0.f;  mem.y -= s1 ? THRESH : 0.f;
        mem.z -= s2 ? THRESH : 0.f;  mem.w -= s3 ? THRESH : 0.f;

        // ---- ballots + outputs ----
        const unsigned long long B0 = __ballot(s0), B1 = __ballot(s1);
        const unsigned long long B2 = __ballot(s2), B3 = __ballot(s3);
        const int pre = __popcll(B0 & below) + __popcll(B1 & below) +
                        __popcll(B2 & below) + __popcll(B3 & below);
        if (lane == 0)
            wcnt[wave] = __popcll(B0) + __popcll(B1) + __popcll(B2) + __popcll(B3);

        const f32x4 sp = {s0 ? 1.f : 0.f, s1 ? 1.f : 0.f,
                          s2 ? 1.f : 0.f, s3 ? 1.f : 0.f};
        *(f32x4*)&spk_out[(size_t)t * N_SIZE + base] = sp;
        *(f32x4*)&mem_out[(size_t)t * N_SIZE + base] = mem;

        __syncthreads();   // bar1: wcnt visible; gather reads of lst[buf] done

        int woff = 0, tt = 0;
#pragma unroll
        for (int w = 0; w < 16; ++w) {
            const int cw = wcnt[w];
            if (w < wave) woff += cw;
            tt += cw;
        }
        int* nxt = lst[buf ^ 1];
        int off = woff + pre;
        if (s0) nxt[off++] = base + 0;
        if (s1) nxt[off++] = base + 1;
        if (s2) nxt[off++] = base + 2;
        if (s3) nxt[off++] = base + 3;
        if (tid < 12) nxt[tt + tid] = N_SIZE;   // pad -> zero row

        __syncthreads();   // bar2: next list ready

        tot = tt;
        buf ^= 1;
    }

    if (t1 != N_STEPS) {    // hand off to second dispatch
        *(f32x4*)&smem[base] = mem;
        for (int i = tid; i < N_SIZE + 12; i += 1024) slst[i] = lst[buf][i];
        if (tid == 0) slst[N_SIZE + 12] = tot;
    }
    if (BURN && tid == 0)
        __hip_atomic_store(flag, 1u, __ATOMIC_RELEASE, __HIP_MEMORY_SCOPE_AGENT);
}

// ---------------- fallback: single-WG scan (no/partial ws) ----------------
template <int USE_WST>
__global__ __launch_bounds__(1024) void k_scan1(const float* __restrict__ WsT,
                                                const float* __restrict__ W,
                                                float* __restrict__ spk_out,
                                                float* __restrict__ mem_out) {
    __shared__ int lists[2][N_SIZE];
    __shared__ int wcnt[16];
    const int tid = threadIdx.x;
    const int wave = tid >> 6;
    const int lane = tid & 63;
    const int base = tid << 2;
    const unsigned long long below = (lane == 0) ? 0ULL : (~0ULL >> (64 - lane));

    float4 mem = {0.f, 0.f, 0.f, 0.f};
    int cnt = 0, cur = 0;
    for (int t = 0; t < N_STEPS; ++t) {
        float* mrow = &mem_out[(size_t)t * N_SIZE + base];
        float4 c = *(const float4*)mrow;
        const int* lstp = lists[cur];
        for (int i = 0; i < cnt; ++i) {
            const int s = lstp[i];
            float4 w0;
            if (USE_WST) {
                w0 = *(const float4*)&WsT[(size_t)s * N_SIZE + base];
            } else {
                w0.x = W[(size_t)(base + 0) * WROW + N_SIZE + s];
                w0.y = W[(size_t)(base + 1) * WROW + N_SIZE + s];
                w0.z = W[(size_t)(base + 2) * WROW + N_SIZE + s];
                w0.w = W[(size_t)(base + 3) * WROW + N_SIZE + s];
            }
            ADD4(c, w0)
        }
        ADD4(mem, c)
        const bool s0 = mem.x > THRESH, s1 = mem.y > THRESH;
        const bool s2 = mem.z > THRESH, s3 = mem.w > THRESH;
        mem.x -= s0 ? THRESH : 0.f;  mem.y -= s1 ? THRESH : 0.f;
        mem.z -= s2 ? THRESH : 0.f;  mem.w -= s3 ? THRESH : 0.f;
        const float4 spkv = {s0 ? 1.f : 0.f, s1 ? 1.f : 0.f,
                             s2 ? 1.f : 0.f, s3 ? 1.f : 0.f};
        *(float4*)&spk_out[(size_t)t * N_SIZE + base] = spkv;
        *(float4*)mrow = mem;
        const unsigned long long b0 = __ballot(s0), b1 = __ballot(s1);
        const unsigned long long b2 = __ballot(s2), b3 = __ballot(s3);
        const int pre = __popcll(b0 & below) + __popcll(b1 & below) +
                        __popcll(b2 & below) + __popcll(b3 & below);
        if (lane == 0)
            wcnt[wave] = __popcll(b0) + __popcll(b1) + __popcll(b2) + __popcll(b3);
        __syncthreads();
        int woff = 0, total = 0;
#pragma unroll
        for (int wv = 0; wv < 16; ++wv) {
            const int cw = wcnt[wv];
            if (wv < wave) woff += cw;
            total += cw;
        }
        int* nxt = lists[cur ^ 1];
        int off = woff + pre;
        if (s0) nxt[off++] = base;
        if (s1) nxt[off++] = base + 1;
        if (s2) nxt[off++] = base + 2;
        if (s3) nxt[off++] = base + 3;
        __syncthreads();
        cnt = total;
        cur ^= 1;
    }
}

extern "C" void kernel_launch(void* const* d_in, const int* in_sizes, int n_in,
                              void* d_out, int out_size, void* d_ws, size_t ws_size,
                              hipStream_t stream) {
    const float* x = (const float*)d_in[0];
    const float* W = (const float*)d_in[1];
    float* spk_out = (float*)d_out;
    float* mem_out = spk_out + (size_t)N_STEPS * N_SIZE;
    float* WsT = (float*)d_ws;
    unsigned* flag = (unsigned*)((char*)d_ws + FLAG_OFF);
    float* smem = (float*)((char*)d_ws + SMEM_OFF);
    int* slst = (int*)((char*)d_ws + SLST_OFF);
    const bool full = ws_size >= FULL_WS;
    const bool use_wst = ws_size >= (size_t)N_SIZE * N_SIZE * 4;

    if (full) {
        k_zero<<<17, 256, 0, stream>>>(WsT, flag);
        k_transpose<<<dim3(N_SIZE / 32, N_SIZE / 32), dim3(32, 8), 0, stream>>>(W, WsT);
    } else if (use_wst) {
        k_transpose<<<dim3(N_SIZE / 32, N_SIZE / 32), dim3(32, 8), 0, stream>>>(W, WsT);
    }

    k_gemm<<<dim3(N_SIZE / BN, N_STEPS / BM, 2), 128, 0, stream>>>(x, W, mem_out, spk_out);
    k_reduce<<<(N_STEPS * N_SIZE) / (256 * 4), 256, 0, stream>>>(mem_out, spk_out);

    if (full) {
        // A: no burners, steps 0..255
        k_scan_ab<0><<<1, 1024, 0, stream>>>(WsT, spk_out, mem_out, smem, slst,
                                             flag, 0, 256);
        // B: 128 burner blocks, steps 256..511
        k_scan_ab<1><<<129, 1024, 0, stream>>>(WsT, spk_out, mem_out, smem, slst,
                                               flag, 256, 512);
    } else if (use_wst) {
        k_scan1<1><<<1, 1024, 0, stream>>>(WsT, W, spk_out, mem_out);
    } else {
        k_scan1<0><<<1, 1024, 0, stream>>>(WsT, W, spk_out, mem_out);
    }
}